// Round 1
// baseline (18491.760 us; speedup 1.0000x reference)
//
#include <hip/hip_runtime.h>

typedef unsigned short u16;
typedef __attribute__((ext_vector_type(8))) short short8v;
typedef __attribute__((ext_vector_type(4))) float f32x4;

#define NB 64
#define NT 256
#define NM 512
#define NH 256

__device__ __forceinline__ float bf2f(u16 u) {
  union { unsigned i; float f; } c; c.i = ((unsigned)u) << 16; return c.f;
}
__device__ __forceinline__ u16 f2bf(float f) {
  union { float fv; unsigned i; } c; c.fv = f;
  unsigned i = c.i;
  return (u16)((i + 0x7fffu + ((i >> 16) & 1u)) >> 16);
}
__device__ __forceinline__ float tanh_fast(float x) {
  // tanh(x) = 1 - 2/(1+e^{2x}),  e^{2x} = exp2(2*log2e*x)
  return 1.0f - 2.0f * __builtin_amdgcn_rcpf(1.0f + __builtin_amdgcn_exp2f(2.8853900817779268f * x));
}
__device__ __forceinline__ float sigmoid_fast(float x) {
  return __builtin_amdgcn_rcpf(1.0f + __builtin_amdgcn_exp2f(-1.4426950408889634f * x));
}

__global__ void convert_f32_bf16(const float* __restrict__ in, u16* __restrict__ out, int n) {
  int i = blockIdx.x * blockDim.x + threadIdx.x;
  if (i < n) out[i] = f2bf(in[i]);
}

// C[r,n] = sum_k A[r,k]*Bm[n,k];  A:[16384,512] Bm:[512,512] C:[16384,512], bf16
__global__ __launch_bounds__(256) void gemm_y1(const u16* __restrict__ A,
                                               const u16* __restrict__ Bm,
                                               u16* __restrict__ C) {
  const int w = threadIdx.x >> 6;
  const int l = threadIdx.x & 63;
  const int kg = l >> 4;            // 0..3 k-group
  const int r16 = l & 15;
  const int rowbase = blockIdx.x * 64 + w * 16;
  const int colbase = blockIdx.y * 64;
  const u16* ap = A + (size_t)(rowbase + r16) * 512 + kg * 8;
  f32x4 acc0 = {0,0,0,0}, acc1 = {0,0,0,0}, acc2 = {0,0,0,0}, acc3 = {0,0,0,0};
  for (int k = 0; k < 512; k += 32) {
    short8v af = *(const short8v*)(ap + k);
    const u16* bp = Bm + (size_t)(colbase + r16) * 512 + kg * 8 + k;
    short8v b0 = *(const short8v*)(bp);
    short8v b1 = *(const short8v*)(bp + 16 * 512);
    short8v b2 = *(const short8v*)(bp + 32 * 512);
    short8v b3 = *(const short8v*)(bp + 48 * 512);
    acc0 = __builtin_amdgcn_mfma_f32_16x16x32_bf16(af, b0, acc0, 0, 0, 0);
    acc1 = __builtin_amdgcn_mfma_f32_16x16x32_bf16(af, b1, acc1, 0, 0, 0);
    acc2 = __builtin_amdgcn_mfma_f32_16x16x32_bf16(af, b2, acc2, 0, 0, 0);
    acc3 = __builtin_amdgcn_mfma_f32_16x16x32_bf16(af, b3, acc3, 0, 0, 0);
  }
  const int rl = (l >> 4) * 4;
  #pragma unroll
  for (int j = 0; j < 4; ++j) {
    int r = rowbase + rl + j;
    C[(size_t)r * 512 + colbase +  0 + r16] = f2bf(acc0[j]);
    C[(size_t)r * 512 + colbase + 16 + r16] = f2bf(acc1[j]);
    C[(size_t)r * 512 + colbase + 32 + r16] = f2bf(acc2[j]);
    C[(size_t)r * 512 + colbase + 48 + r16] = f2bf(acc3[j]);
  }
}

__device__ __forceinline__ void batch_barrier(unsigned* c, unsigned target) {
  __syncthreads();
  if (threadIdx.x == 0) {
    __hip_atomic_fetch_add(c, 1u, __ATOMIC_RELEASE, __HIP_MEMORY_SCOPE_AGENT);
    while (__hip_atomic_load(c, __ATOMIC_RELAXED, __HIP_MEMORY_SCOPE_AGENT) < target)
      __builtin_amdgcn_s_sleep(1);
    __threadfence();  // acquire: invalidate L1/L2 path before dependent reads
  }
  __syncthreads();
}

__global__ __launch_bounds__(512) void attn_scan(
    const u16* __restrict__ y1bf,    // [B,T,M]
    const u16* __restrict__ encbf,   // [B,T,M]
    const u16* __restrict__ Wdbf,    // [M,512]
    const u16* __restrict__ Whhbf,   // [1024,256]
    const float* __restrict__ Wd_b,  // [512]
    const float* __restrict__ vd,    // [512]
    const float* __restrict__ wtw,   // [513]
    const float* __restrict__ wtb,   // [1]
    const float* __restrict__ Wih,   // [1024]
    const float* __restrict__ bih,   // [1024]
    const float* __restrict__ bhh,   // [1024]
    const float* __restrict__ yin,   // [B,T]
    float* __restrict__ gpx1,        // [B,4,512]
    float* __restrict__ gl,          // [B,256]
    float* __restrict__ gct,         // [B,512]
    float* __restrict__ gd,          // [2,B,256]
    unsigned* __restrict__ ctr,      // [B,16]
    float* __restrict__ out)         // [B,512]
{
  const int tid = threadIdx.x;
  const int bid = blockIdx.x;
  // keep the 4 WGs of a batch on one XCD (heuristic: XCD = bid % 8)
  const int xcd = bid & 7, ii = bid >> 3;
  const int b = (xcd << 3) | (ii >> 2);
  const int q = ii & 3;
  const int w = tid >> 6, l = tid & 63;

  __shared__ float vd_l[NM];
  __shared__ float wtw_l[NM + 1];
  __shared__ float x1_l[NM];
  __shared__ float beta_l[NT];
  __shared__ float red_l[512];
  __shared__ float ct_l[NM];
  __shared__ float dl[NH];
  __shared__ float gbuf[256];
  __shared__ float dnew_l[64], snew_l[64];
  __shared__ float scal[1];

  vd_l[tid] = vd[tid];
  wtw_l[tid] = wtw[tid];
  if (tid == 0) wtw_l[NM] = wtw[NM];
  float s_reg = 0.0f;   // tid<64: own s[h], h = q*64+tid
  float out_acc = 0.0f; // tid<128: own sum_t c_t[m], m = q*128+tid
  __syncthreads();

  unsigned* c0 = &ctr[b * 16 + 0];
  unsigned* c1 = &ctr[b * 16 + 1];
  unsigned* c2 = &ctr[b * 16 + 2];

  #pragma unroll 1
  for (int t = 0; t < NT; ++t) {
    const unsigned tgt = 4u * (t + 1);
    // ---- P1: x1 = Wd_b + sum_q partials; then l_it over own te-slice ----
    {
      const float* p = gpx1 + b * 2048 + tid;
      x1_l[tid] = Wd_b[tid] + p[0] + p[512] + p[1024] + p[1536];
    }
    __syncthreads();
    #pragma unroll 1
    for (int i = 0; i < 8; ++i) {
      int te = q * 64 + w * 8 + i;
      const u16* yr = y1bf + ((size_t)(b * NT + te)) * NM + l * 8;
      short8v yv = *(const short8v*)yr;
      float a = 0.0f;
      #pragma unroll
      for (int j = 0; j < 8; ++j) {
        int m = l * 8 + j;
        float z = tanh_fast(x1_l[m] + bf2f((u16)yv[j]));
        a = fmaf(z, vd_l[m], a);
      }
      #pragma unroll
      for (int off = 32; off > 0; off >>= 1) a += __shfl_xor(a, off, 64);
      if (l == 0) gl[b * NT + te] = a;
    }
    batch_barrier(c0, tgt);

    // ---- P2: softmax (redundant per WG) + c_t over own m-slice ----
    float myl = 0.0f;
    if (tid < 256) { myl = gl[b * NT + tid]; red_l[tid] = myl; }
    __syncthreads();
    for (int off = 128; off > 0; off >>= 1) {
      if (tid < off) red_l[tid] = fmaxf(red_l[tid], red_l[tid + off]);
      __syncthreads();
    }
    float mx = red_l[0];
    __syncthreads();
    float pexp = 0.0f;
    if (tid < 256) { pexp = __builtin_amdgcn_exp2f((myl - mx) * 1.4426950408889634f); red_l[tid] = pexp; }
    __syncthreads();
    for (int off = 128; off > 0; off >>= 1) {
      if (tid < off) red_l[tid] += red_l[tid + off];
      __syncthreads();
    }
    float denom = red_l[0];
    if (tid < 256) beta_l[tid] = pexp * __builtin_amdgcn_rcpf(denom);
    __syncthreads();
    {
      int tg = tid >> 7, ml = tid & 127;
      int m = q * 128 + ml;
      const u16* ep = encbf + ((size_t)(b * NT + tg * 64)) * NM + m;
      float a = 0.0f;
      #pragma unroll 8
      for (int i2 = 0; i2 < 64; ++i2)
        a = fmaf(bf2f(ep[(size_t)i2 * NM]), beta_l[tg * 64 + i2], a);
      red_l[tid] = a;
    }
    __syncthreads();
    if (tid < 128) {
      float ctv = red_l[tid] + red_l[128 + tid] + red_l[256 + tid] + red_l[384 + tid];
      gct[b * NM + q * 128 + tid] = ctv;
      out_acc += ctv;
    }
    batch_barrier(c1, tgt);

    // ---- P3: y_tilda + LSTM gates (own h-slice) + next-step x1 partial ----
    ct_l[tid] = gct[b * NM + tid];
    if (tid < 256) dl[tid] = gd[(t & 1) * (NB * NH) + b * NH + tid];
    __syncthreads();
    {
      float pr = ct_l[tid] * wtw_l[tid];
      #pragma unroll
      for (int off = 32; off > 0; off >>= 1) pr += __shfl_xor(pr, off, 64);
      if (l == 0) red_l[w] = pr;
    }
    __syncthreads();
    if (tid == 0) {
      float yt = red_l[0] + red_l[1] + red_l[2] + red_l[3] + red_l[4] + red_l[5] + red_l[6] + red_l[7];
      yt += wtw_l[NM] * yin[b * NT + t] + wtb[0];
      scal[0] = yt;
    }
    __syncthreads();
    float yt = scal[0];
    {
      int j = tid >> 1, half = tid & 1;
      int r = ((j >> 6) << 8) + q * 64 + (j & 63);
      const u16* wr = Whhbf + (size_t)r * NH + half * 128;
      float a = 0.0f;
      #pragma unroll
      for (int c8 = 0; c8 < 16; ++c8) {
        short8v wv = *(const short8v*)(wr + c8 * 8);
        #pragma unroll
        for (int jj = 0; jj < 8; ++jj)
          a = fmaf(bf2f((u16)wv[jj]), dl[half * 128 + c8 * 8 + jj], a);
      }
      a += __shfl_xor(a, 1, 64);
      if (half == 0) gbuf[j] = a + yt * Wih[r] + bih[r] + bhh[r];
    }
    __syncthreads();
    if (tid < 64) {
      int h = q * 64 + tid;
      float ig = sigmoid_fast(gbuf[tid]);
      float fg = sigmoid_fast(gbuf[64 + tid]);
      float gg = tanh_fast(gbuf[128 + tid]);
      float og = sigmoid_fast(gbuf[192 + tid]);
      float sn = fg * s_reg + ig * gg;
      s_reg = sn;
      float dn = og * tanh_fast(sn);
      gd[((t + 1) & 1) * (NB * NH) + b * NH + h] = dn;
      dnew_l[tid] = dn;
      snew_l[tid] = sn;
    }
    __syncthreads();
    {
      // partial x1 for next step over own (d,s) k-slice; m = tid
      const u16* wd_d = Wdbf + (size_t)tid * 512 + q * 64;
      const u16* wd_s = Wdbf + (size_t)tid * 512 + 256 + q * 64;
      float a = 0.0f;
      #pragma unroll
      for (int c8 = 0; c8 < 8; ++c8) {
        short8v wv = *(const short8v*)(wd_d + c8 * 8);
        short8v wv2 = *(const short8v*)(wd_s + c8 * 8);
        #pragma unroll
        for (int jj = 0; jj < 8; ++jj) {
          a = fmaf(bf2f((u16)wv[jj]), dnew_l[c8 * 8 + jj], a);
          a = fmaf(bf2f((u16)wv2[jj]), snew_l[c8 * 8 + jj], a);
        }
      }
      gpx1[b * 2048 + q * 512 + tid] = a;
    }
    batch_barrier(c2, tgt);
  }
  if (tid < 128) out[b * NM + q * 128 + tid] = out_acc;
}

extern "C" void kernel_launch(void* const* d_in, const int* in_sizes, int n_in,
                              void* d_out, int out_size, void* d_ws, size_t ws_size,
                              hipStream_t stream) {
  const float* enc  = (const float*)d_in[0];
  const float* yin  = (const float*)d_in[1];
  const float* Wd_w = (const float*)d_in[2];
  const float* Wd_b = (const float*)d_in[3];
  const float* Ud_w = (const float*)d_in[4];
  const float* vd_w = (const float*)d_in[5];
  const float* wt_w = (const float*)d_in[6];
  const float* wt_b = (const float*)d_in[7];
  const float* Wih  = (const float*)d_in[8];
  const float* Whh  = (const float*)d_in[9];
  const float* bih  = (const float*)d_in[10];
  const float* bhh  = (const float*)d_in[11];

  char* ws = (char*)d_ws;
  u16*   y1bf  = (u16*)(ws);                      // 16,777,216 B
  u16*   encbf = (u16*)(ws + 16777216);           // 16,777,216 B
  u16*   udbf  = (u16*)(ws + 33554432);           // 524,288 B
  u16*   wdbf  = (u16*)(ws + 34078720);           // 524,288 B
  u16*   whhbf = (u16*)(ws + 34603008);           // 524,288 B
  float* gpx1  = (float*)(ws + 35127296);         // 524,288 B
  float* gl    = (float*)(ws + 35651584);         // 65,536 B
  float* gct   = (float*)(ws + 35717120);         // 131,072 B
  float* gd    = (float*)(ws + 35848192);         // 2*65,536 B
  unsigned* ctr = (unsigned*)(ws + 35979264);     // 4,096 B

  // zero the mutable state: gpx1, gl, gct, gd[2], ctr
  hipMemsetAsync(ws + 35127296, 0, 856064, stream);

  convert_f32_bf16<<<8388608 / 256, 256, 0, stream>>>(enc, encbf, 8388608);
  convert_f32_bf16<<<262144 / 256, 256, 0, stream>>>(Ud_w, udbf, 262144);
  convert_f32_bf16<<<262144 / 256, 256, 0, stream>>>(Wd_w, wdbf, 262144);
  convert_f32_bf16<<<262144 / 256, 256, 0, stream>>>(Whh, whhbf, 262144);
  gemm_y1<<<dim3(256, 8), 256, 0, stream>>>(encbf, udbf, y1bf);
  attn_scan<<<256, 512, 0, stream>>>(y1bf, encbf, wdbf, whhbf, Wd_b, vd_w, wt_w,
                                     wt_b, Wih, bih, bhh, yin, gpx1, gl, gct, gd,
                                     ctr, (float*)d_out);
}

// Round 2
// 4886.324 us; speedup vs baseline: 3.7844x; 3.7844x over previous
//
#include <hip/hip_runtime.h>

typedef unsigned short u16;
typedef __attribute__((ext_vector_type(8))) short short8v;
typedef __attribute__((ext_vector_type(4))) float f32x4;

#define NB 64
#define NT 256
#define NM 512
#define NH 256

#define K2 2.8853900817779268f   // 2*log2(e)
#define LOG2E 1.4426950408889634f

__device__ __forceinline__ float bf2f(u16 u) {
  union { unsigned i; float f; } c; c.i = ((unsigned)u) << 16; return c.f;
}
__device__ __forceinline__ u16 f2bf(float f) {
  union { float fv; unsigned i; } c; c.fv = f;
  unsigned i = c.i;
  return (u16)((i + 0x7fffu + ((i >> 16) & 1u)) >> 16);
}
__device__ __forceinline__ float tanh_fast(float x) {
  return 1.0f - 2.0f * __builtin_amdgcn_rcpf(1.0f + __builtin_amdgcn_exp2f(K2 * x));
}
__device__ __forceinline__ float sigmoid_fast(float x) {
  return __builtin_amdgcn_rcpf(1.0f + __builtin_amdgcn_exp2f(-LOG2E * x));
}
// system-scope relaxed (uncached: sc0 sc1, bypass L1/L2, NO cache invalidation)
__device__ __forceinline__ float uload(const float* p) {
  return __hip_atomic_load(p, __ATOMIC_RELAXED, __HIP_MEMORY_SCOPE_SYSTEM);
}
__device__ __forceinline__ void ustore(float* p, float v) {
  __hip_atomic_store(p, v, __ATOMIC_RELAXED, __HIP_MEMORY_SCOPE_SYSTEM);
}

__global__ void convert_f32_bf16(const float* __restrict__ in, u16* __restrict__ out, int n) {
  int i = blockIdx.x * blockDim.x + threadIdx.x;
  if (i < n) out[i] = f2bf(in[i]);
}

// y1' = K2 * enc @ Ud^T  (bf16 out, prescaled for exp2-based tanh)
__global__ __launch_bounds__(256) void gemm_y1(const u16* __restrict__ A,
                                               const u16* __restrict__ Bm,
                                               u16* __restrict__ C) {
  const int w = threadIdx.x >> 6;
  const int l = threadIdx.x & 63;
  const int kg = l >> 4;
  const int r16 = l & 15;
  const int rowbase = blockIdx.x * 64 + w * 16;
  const int colbase = blockIdx.y * 64;
  const u16* ap = A + (size_t)(rowbase + r16) * 512 + kg * 8;
  f32x4 acc0 = {0,0,0,0}, acc1 = {0,0,0,0}, acc2 = {0,0,0,0}, acc3 = {0,0,0,0};
  for (int k = 0; k < 512; k += 32) {
    short8v af = *(const short8v*)(ap + k);
    const u16* bp = Bm + (size_t)(colbase + r16) * 512 + kg * 8 + k;
    short8v b0 = *(const short8v*)(bp);
    short8v b1 = *(const short8v*)(bp + 16 * 512);
    short8v b2 = *(const short8v*)(bp + 32 * 512);
    short8v b3 = *(const short8v*)(bp + 48 * 512);
    acc0 = __builtin_amdgcn_mfma_f32_16x16x32_bf16(af, b0, acc0, 0, 0, 0);
    acc1 = __builtin_amdgcn_mfma_f32_16x16x32_bf16(af, b1, acc1, 0, 0, 0);
    acc2 = __builtin_amdgcn_mfma_f32_16x16x32_bf16(af, b2, acc2, 0, 0, 0);
    ac3:
    acc3 = __builtin_amdgcn_mfma_f32_16x16x32_bf16(af, b3, acc3, 0, 0, 0);
  }
  const int rl = (l >> 4) * 4;
  #pragma unroll
  for (int j = 0; j < 4; ++j) {
    int r = rowbase + rl + j;
    C[(size_t)r * 512 + colbase +  0 + r16] = f2bf(K2 * acc0[j]);
    C[(size_t)r * 512 + colbase + 16 + r16] = f2bf(K2 * acc1[j]);
    C[(size_t)r * 512 + colbase + 32 + r16] = f2bf(K2 * acc2[j]);
    C[(size_t)r * 512 + colbase + 48 + r16] = f2bf(K2 * acc3[j]);
  }
}

// w_enc[b,te] = sum_m enc[b,te,m] * wtw[m]
__global__ __launch_bounds__(256) void wenc_kernel(const u16* __restrict__ encbf,
                                                   const float* __restrict__ wtw,
                                                   float* __restrict__ gwenc) {
  int b = blockIdx.x, te = threadIdx.x;
  const u16* ep = encbf + ((size_t)(b * NT + te)) * NM;
  float a = 0.0f;
  for (int c8 = 0; c8 < 64; ++c8) {
    short8v v = *(const short8v*)(ep + c8 * 8);
    #pragma unroll
    for (int jj = 0; jj < 8; ++jj) a = fmaf(bf2f((u16)v[jj]), wtw[c8 * 8 + jj], a);
  }
  gwenc[b * NT + te] = a;
}

__device__ __forceinline__ void batch_barrier(unsigned* c, unsigned target) {
  asm volatile("s_waitcnt vmcnt(0)" ::: "memory");
  __syncthreads();
  if (threadIdx.x == 0) {
    __hip_atomic_fetch_add(c, 1u, __ATOMIC_RELAXED, __HIP_MEMORY_SCOPE_SYSTEM);
    while (__hip_atomic_load(c, __ATOMIC_RELAXED, __HIP_MEMORY_SCOPE_SYSTEM) < target)
      __builtin_amdgcn_s_sleep(2);
  }
  __syncthreads();
}

__global__ __launch_bounds__(512) void attn_scan(
    const u16* __restrict__ y1bf,    // [B,T,M] prescaled by K2
    const u16* __restrict__ encbf,   // [B,T,M]
    const u16* __restrict__ Wdbf,    // [M,512]
    const u16* __restrict__ Whhbf,   // [1024,256]
    const float* __restrict__ Wd_b,  // [512]
    const float* __restrict__ vd,    // [512]
    const float* __restrict__ wtw,   // [513]
    const float* __restrict__ wtb,   // [1]
    const float* __restrict__ Wih,   // [1024]
    const float* __restrict__ bih,   // [1024]
    const float* __restrict__ bhh,   // [1024]
    const float* __restrict__ yin,   // [B,T]
    const float* __restrict__ gwenc, // [B,256]
    float* __restrict__ gpx1,        // [B,4,512]
    float* __restrict__ gl,          // [B,256]
    float* __restrict__ gd,          // [2,B,256]
    unsigned* __restrict__ ctr,      // [B,16]
    float* __restrict__ out)         // [B,512]
{
  extern __shared__ char ldsraw[];
  u16* y1_l  = (u16*)ldsraw;             // [64][512]   65536 B
  u16* enc_t = (u16*)(ldsraw + 65536);   // [128][256] swizzled, 65536 B

  __shared__ float x1_l[NM];
  __shared__ float beta_l[NT];
  __shared__ float red_l[512];
  __shared__ float red2[16];
  __shared__ float dl[NH];
  __shared__ float gbuf[256];
  __shared__ float dnew_l[64], snew_l[64];
  __shared__ float w_enc_l[NT];

  const int tid = threadIdx.x;
  const int bid = blockIdx.x;
  const int xcd = bid & 7, ii = bid >> 3;
  const int b = (xcd << 3) | (ii >> 2);   // 4 WGs of a batch near each other
  const int q = ii & 3;
  const int w = tid >> 6, l = tid & 63;

  // ---- one-time staging ----
  // y1 slice (rows q*64 .. q*64+63, all m): contiguous 32768 elems
  {
    const u16* src = y1bf + ((size_t)(b * NT + q * 64) << 9);
    #pragma unroll
    for (int it = 0; it < 8; ++it) {
      int flat = it * 4096 + tid * 8;
      *(short8v*)(y1_l + flat) = *(const short8v*)(src + flat);
    }
  }
  // enc slice transposed + unit-swizzled: enc_t[ml][ (u^(ml&7))*8 + (te&7) ] = enc[b][te][q*128+ml]
  #pragma unroll
  for (int it = 0; it < 8; ++it) {
    int flat = it * 4096 + tid * 8;      // over [256 te][128 ml]
    int te = flat >> 7, ml0 = flat & 127;
    short8v v = *(const short8v*)(encbf + ((size_t)(b * NT + te) << 9) + q * 128 + ml0);
    int u = te >> 3, tlo = te & 7;
    #pragma unroll
    for (int jj = 0; jj < 8; ++jj) {
      int ml = ml0 + jj;
      enc_t[ml * 256 + ((u ^ (ml & 7)) << 3) + tlo] = (u16)v[jj];
    }
  }
  // constants to registers
  float vr[8];
  #pragma unroll
  for (int j = 0; j < 8; ++j) vr[j] = vd[l * 8 + j];
  float sv = 0.0f;
  #pragma unroll
  for (int j = 0; j < 8; ++j) sv += vr[j];
  #pragma unroll
  for (int off = 32; off > 0; off >>= 1) sv += __shfl_xor(sv, off, 64);
  const float Svd = sv;                      // identical in every wave
  const float wdb_r = Wd_b[tid];
  const float wtw512 = wtw[NM];
  const float wtb0 = wtb[0];
  if (tid < 256) w_enc_l[tid] = gwenc[b * NT + tid];
  // LSTM row constants (thread -> gate row r)
  const int jrow = tid >> 1, half = tid & 1;
  const int r = ((jrow >> 6) << 8) + q * 64 + (jrow & 63);
  const float wih_r = Wih[r];
  const float bb_r = bih[r] + bhh[r];

  float s_reg = 0.0f;   // tid<64: own c-state
  float out_acc = 0.0f; // tid<128: own sum_t c_t[m]
  __syncthreads();

  unsigned* c0 = &ctr[b * 16 + 0];
  unsigned* c2 = &ctr[b * 16 + 1];

  #pragma unroll 1
  for (int t = 0; t < NT; ++t) {
    const unsigned tgt = 4u * (t + 1);
    // ---- P1: x1 (sum partials, prescaled), prefetch d, l_it over te-slice ----
    if (tid < 256) dl[tid] = uload(&gd[(t & 1) * (NB * NH) + b * NH + tid]);
    {
      const float* p = gpx1 + b * 2048 + tid;
      float a0 = uload(p), a1 = uload(p + 512), a2 = uload(p + 1024), a3 = uload(p + 1536);
      x1_l[tid] = K2 * (wdb_r + ((a0 + a1) + (a2 + a3)));
    }
    __syncthreads();
    float xr[8];
    #pragma unroll
    for (int j = 0; j < 8; ++j) xr[j] = x1_l[l * 8 + j];
    #pragma unroll 1
    for (int i = 0; i < 8; ++i) {
      int te_loc = w * 8 + i;
      short8v yv = *(const short8v*)(y1_l + te_loc * 512 + l * 8);
      float a = 0.0f;
      #pragma unroll
      for (int j = 0; j < 8; ++j) {
        float e = __builtin_amdgcn_exp2f(xr[j] + bf2f((u16)yv[j]));
        a = fmaf(vr[j], __builtin_amdgcn_rcpf(1.0f + e), a);
      }
      #pragma unroll
      for (int off = 32; off > 0; off >>= 1) a += __shfl_xor(a, off, 64);
      if (l == 0) ustore(&gl[b * NT + q * 64 + te_loc], Svd - 2.0f * a);
    }
    batch_barrier(c0, tgt);

    // ---- P2: softmax + yt (redundant), ct slice, LSTM slice, x1 partial ----
    float myl = -1e30f;
    if (tid < 256) myl = uload(&gl[b * NT + tid]);
    float m1 = myl;
    #pragma unroll
    for (int off = 32; off > 0; off >>= 1) m1 = fmaxf(m1, __shfl_xor(m1, off, 64));
    if (l == 0) red2[w] = m1;
    __syncthreads();
    const float mx = fmaxf(fmaxf(red2[0], red2[1]), fmaxf(red2[2], red2[3]));
    float pexp = 0.0f;
    if (tid < 256) pexp = __builtin_amdgcn_exp2f((myl - mx) * LOG2E);
    float s1 = pexp;
    #pragma unroll
    for (int off = 32; off > 0; off >>= 1) s1 += __shfl_xor(s1, off, 64);
    if (l == 0) red2[4 + w] = s1;
    __syncthreads();
    const float denom = (red2[4] + red2[5]) + (red2[6] + red2[7]);
    const float rden = __builtin_amdgcn_rcpf(denom);
    float mybeta = pexp * rden;
    if (tid < 256) beta_l[tid] = mybeta;
    float yp = (tid < 256) ? mybeta * w_enc_l[tid] : 0.0f;
    #pragma unroll
    for (int off = 32; off > 0; off >>= 1) yp += __shfl_xor(yp, off, 64);
    if (l == 0) red2[8 + w] = yp;
    __syncthreads();
    const float yt = (red2[8] + red2[9]) + (red2[10] + red2[11])
                   + wtw512 * yin[b * NT + t] + wtb0;
    // c_t over own m-slice from swizzled enc_t
    {
      int tg = tid >> 7, ml = tid & 127;
      const u16* er = enc_t + ml * 256;
      int swz = ml & 7;
      float a = 0.0f;
      #pragma unroll
      for (int jj2 = 0; jj2 < 8; ++jj2) {
        int u = tg * 8 + jj2;
        short8v ev = *(const short8v*)(er + ((u ^ swz) << 3));
        #pragma unroll
        for (int jj = 0; jj < 8; ++jj)
          a = fmaf(bf2f((u16)ev[jj]), beta_l[(u << 3) + jj], a);
      }
      red_l[tid] = a;
    }
    // LSTM gates: row r, halves of k
    {
      const u16* wr = Whhbf + (size_t)r * NH + half * 128;
      float a = 0.0f;
      #pragma unroll
      for (int c8 = 0; c8 < 16; ++c8) {
        short8v wv = *(const short8v*)(wr + c8 * 8);
        #pragma unroll
        for (int jj = 0; jj < 8; ++jj)
          a = fmaf(bf2f((u16)wv[jj]), dl[half * 128 + c8 * 8 + jj], a);
      }
      a += __shfl_xor(a, 1, 64);
      if (half == 0) gbuf[jrow] = a + yt * wih_r + bb_r;
    }
    __syncthreads();
    if (tid < 128) {
      float ctv = (red_l[tid] + red_l[128 + tid]) + (red_l[256 + tid] + red_l[384 + tid]);
      out_acc += ctv;
    }
    if (tid < 64) {
      float ig = sigmoid_fast(gbuf[tid]);
      float fg = sigmoid_fast(gbuf[64 + tid]);
      float gg = tanh_fast(gbuf[128 + tid]);
      float og = sigmoid_fast(gbuf[192 + tid]);
      float sn = fg * s_reg + ig * gg;
      s_reg = sn;
      float dn = og * tanh_fast(sn);
      ustore(&gd[((t + 1) & 1) * (NB * NH) + b * NH + q * 64 + tid], dn);
      dnew_l[tid] = dn;
      snew_l[tid] = sn;
    }
    __syncthreads();
    {
      // x1 partial for next step over own (d,s) k-slice; m = tid
      const u16* wd_d = Wdbf + (size_t)tid * 512 + q * 64;
      const u16* wd_s = wd_d + 256;
      float a = 0.0f;
      #pragma unroll
      for (int c8 = 0; c8 < 8; ++c8) {
        short8v wv = *(const short8v*)(wd_d + c8 * 8);
        short8v wv2 = *(const short8v*)(wd_s + c8 * 8);
        #pragma unroll
        for (int jj = 0; jj < 8; ++jj) {
          a = fmaf(bf2f((u16)wv[jj]), dnew_l[c8 * 8 + jj], a);
          a = fmaf(bf2f((u16)wv2[jj]), snew_l[c8 * 8 + jj], a);
        }
      }
      ustore(&gpx1[b * 2048 + q * 512 + tid], a);
    }
    batch_barrier(c2, tgt);
  }
  if (tid < 128) out[b * NM + q * 128 + tid] = out_acc;
}

extern "C" void kernel_launch(void* const* d_in, const int* in_sizes, int n_in,
                              void* d_out, int out_size, void* d_ws, size_t ws_size,
                              hipStream_t stream) {
  const float* enc  = (const float*)d_in[0];
  const float* yin  = (const float*)d_in[1];
  const float* Wd_w = (const float*)d_in[2];
  const float* Wd_b = (const float*)d_in[3];
  const float* Ud_w = (const float*)d_in[4];
  const float* vd_w = (const float*)d_in[5];
  const float* wt_w = (const float*)d_in[6];
  const float* wt_b = (const float*)d_in[7];
  const float* Wih  = (const float*)d_in[8];
  const float* Whh  = (const float*)d_in[9];
  const float* bih  = (const float*)d_in[10];
  const float* bhh  = (const float*)d_in[11];

  char* ws = (char*)d_ws;
  u16*   y1bf  = (u16*)(ws);                      // 16,777,216
  u16*   encbf = (u16*)(ws + 16777216);           // 16,777,216
  u16*   udbf  = (u16*)(ws + 33554432);           // 524,288
  u16*   wdbf  = (u16*)(ws + 34078720);           // 524,288
  u16*   whhbf = (u16*)(ws + 34603008);           // 524,288
  float* gpx1  = (float*)(ws + 35127296);         // 524,288
  float* gl    = (float*)(ws + 35651584);         // 65,536
  float* gd    = (float*)(ws + 35717120);         // 131,072
  unsigned* ctr = (unsigned*)(ws + 35848192);     // 4,096
  float* gwenc = (float*)(ws + 35852288);         // 65,536

  // zero mutable state: gpx1, gl, gd, ctr
  hipMemsetAsync(ws + 35127296, 0, 724992, stream);

  convert_f32_bf16<<<8388608 / 256, 256, 0, stream>>>(enc, encbf, 8388608);
  convert_f32_bf16<<<262144 / 256, 256, 0, stream>>>(Ud_w, udbf, 262144);
  convert_f32_bf16<<<262144 / 256, 256, 0, stream>>>(Wd_w, wdbf, 262144);
  convert_f32_bf16<<<262144 / 256, 256, 0, stream>>>(Whh, whhbf, 262144);
  gemm_y1<<<dim3(256, 8), 256, 0, stream>>>(encbf, udbf, y1bf);
  wenc_kernel<<<64, 256, 0, stream>>>(encbf, wt_w, gwenc);

  hipFuncSetAttribute((const void*)attn_scan,
                      hipFuncAttributeMaxDynamicSharedMemorySize, 131072);
  attn_scan<<<256, 512, 131072, stream>>>(y1bf, encbf, wdbf, whhbf, Wd_b, vd_w,
                                          wt_w, wt_b, Wih, bih, bhh, yin, gwenc,
                                          gpx1, gl, gd, ctr, (float*)d_out);
}

// Round 3
// 4420.169 us; speedup vs baseline: 4.1835x; 1.1055x over previous
//
#include <hip/hip_runtime.h>

typedef unsigned short u16;
typedef unsigned int u32;
typedef __attribute__((ext_vector_type(8))) short short8v;
typedef __attribute__((ext_vector_type(4))) float f32x4;
typedef __attribute__((ext_vector_type(4))) unsigned int u32x4;

#define NB 64
#define NT 256
#define NM 512
#define NH 256

#define K2 2.8853900817779268f   // 2*log2(e)
#define LOG2E 1.4426950408889634f

__device__ __forceinline__ float bf2f(u16 u) {
  union { unsigned i; float f; } c; c.i = ((unsigned)u) << 16; return c.f;
}
__device__ __forceinline__ u16 f2bf(float f) {
  union { float fv; unsigned i; } c; c.fv = f;
  unsigned i = c.i;
  return (u16)((i + 0x7fffu + ((i >> 16) & 1u)) >> 16);
}
__device__ __forceinline__ float bits2f(u32 u) {
  union { unsigned i; float f; } c; c.i = u; return c.f;
}
__device__ __forceinline__ float tanh_fast(float x) {
  return 1.0f - 2.0f * __builtin_amdgcn_rcpf(1.0f + __builtin_amdgcn_exp2f(K2 * x));
}
__device__ __forceinline__ float sigmoid_fast(float x) {
  return __builtin_amdgcn_rcpf(1.0f + __builtin_amdgcn_exp2f(-LOG2E * x));
}

// ---- uncached (sc0 sc1: bypass L1/L2, coherence point = IF) helpers ----
__device__ __forceinline__ float unc_ld1(const float* p) {
  float r;
  asm volatile("global_load_dword %0, %1, off sc0 sc1\n\ts_waitcnt vmcnt(0)"
               : "=&v"(r) : "v"(p) : "memory");
  return r;
}
__device__ __forceinline__ void unc_ld1x4(const float* p0, const float* p1,
                                          const float* p2, const float* p3,
                                          float& a0, float& a1, float& a2, float& a3) {
  asm volatile(
      "global_load_dword %0, %4, off sc0 sc1\n\t"
      "global_load_dword %1, %5, off sc0 sc1\n\t"
      "global_load_dword %2, %6, off sc0 sc1\n\t"
      "global_load_dword %3, %7, off sc0 sc1\n\t"
      "s_waitcnt vmcnt(0)"
      : "=&v"(a0), "=&v"(a1), "=&v"(a2), "=&v"(a3)
      : "v"(p0), "v"(p1), "v"(p2), "v"(p3)
      : "memory");
}
__device__ __forceinline__ f32x4 unc_ld4f(const float* p) {
  f32x4 r;
  asm volatile("global_load_dwordx4 %0, %1, off sc0 sc1\n\ts_waitcnt vmcnt(0)"
               : "=&v"(r) : "v"(p) : "memory");
  return r;
}
__device__ __forceinline__ void unc_st1(float* p, float v) {
  asm volatile("global_store_dword %0, %1, off sc0 sc1" :: "v"(p), "v"(v) : "memory");
}
__device__ __forceinline__ void unc_st1u(u32* p, u32 v) {
  asm volatile("global_store_dword %0, %1, off sc0 sc1" :: "v"(p), "v"(v) : "memory");
}
__device__ __forceinline__ void unc_st4(float* p, f32x4 v) {
  asm volatile("global_store_dwordx4 %0, %1, off sc0 sc1" :: "v"(p), "v"(v) : "memory");
}
__device__ __forceinline__ void drain_vmem() {
  asm volatile("s_waitcnt vmcnt(0)" ::: "memory");
}
__device__ __forceinline__ void pollflags(const u32* p, u32 tg) {
  for (;;) {
    u32x4 f;
    asm volatile("global_load_dwordx4 %0, %1, off sc0 sc1\n\ts_waitcnt vmcnt(0)"
                 : "=&v"(f) : "v"(p) : "memory");
    if (f[0] >= tg && f[1] >= tg && f[2] >= tg && f[3] >= tg) break;
    __builtin_amdgcn_s_sleep(1);
  }
}

__global__ void convert_f32_bf16(const float* __restrict__ in, u16* __restrict__ out, int n) {
  int i = blockIdx.x * blockDim.x + threadIdx.x;
  if (i < n) out[i] = f2bf(in[i]);
}

// y1' = K2 * enc @ Ud^T  (bf16 out, prescaled for exp2-based tanh)
__global__ __launch_bounds__(256) void gemm_y1(const u16* __restrict__ A,
                                               const u16* __restrict__ Bm,
                                               u16* __restrict__ C) {
  const int w = threadIdx.x >> 6;
  const int l = threadIdx.x & 63;
  const int kg = l >> 4;
  const int r16 = l & 15;
  const int rowbase = blockIdx.x * 64 + w * 16;
  const int colbase = blockIdx.y * 64;
  const u16* ap = A + (size_t)(rowbase + r16) * 512 + kg * 8;
  f32x4 acc0 = {0,0,0,0}, acc1 = {0,0,0,0}, acc2 = {0,0,0,0}, acc3 = {0,0,0,0};
  for (int k = 0; k < 512; k += 32) {
    short8v af = *(const short8v*)(ap + k);
    const u16* bp = Bm + (size_t)(colbase + r16) * 512 + kg * 8 + k;
    short8v b0 = *(const short8v*)(bp);
    short8v b1 = *(const short8v*)(bp + 16 * 512);
    short8v b2 = *(const short8v*)(bp + 32 * 512);
    short8v b3 = *(const short8v*)(bp + 48 * 512);
    acc0 = __builtin_amdgcn_mfma_f32_16x16x32_bf16(af, b0, acc0, 0, 0, 0);
    acc1 = __builtin_amdgcn_mfma_f32_16x16x32_bf16(af, b1, acc1, 0, 0, 0);
    acc2 = __builtin_amdgcn_mfma_f32_16x16x32_bf16(af, b2, acc2, 0, 0, 0);
    acc3 = __builtin_amdgcn_mfma_f32_16x16x32_bf16(af, b3, acc3, 0, 0, 0);
  }
  #pragma unroll
  for (int j = 0; j < 4; ++j) {
    int r = rowbase + (l >> 4) * 4 + j;
    C[(size_t)r * 512 + colbase +  0 + r16] = f2bf(K2 * acc0[j]);
    C[(size_t)r * 512 + colbase + 16 + r16] = f2bf(K2 * acc1[j]);
    C[(size_t)r * 512 + colbase + 32 + r16] = f2bf(K2 * acc2[j]);
    C[(size_t)r * 512 + colbase + 48 + r16] = f2bf(K2 * acc3[j]);
  }
}

// w_enc[b,te] = sum_m enc[b,te,m] * wtw[m]
__global__ __launch_bounds__(256) void wenc_kernel(const u16* __restrict__ encbf,
                                                   const float* __restrict__ wtw,
                                                   float* __restrict__ gwenc) {
  int b = blockIdx.x, te = threadIdx.x;
  const u16* ep = encbf + ((size_t)(b * NT + te)) * NM;
  float a = 0.0f;
  for (int c8 = 0; c8 < 64; ++c8) {
    short8v v = *(const short8v*)(ep + c8 * 8);
    #pragma unroll
    for (int jj = 0; jj < 8; ++jj) a = fmaf(bf2f((u16)v[jj]), wtw[c8 * 8 + jj], a);
  }
  gwenc[b * NT + te] = a;
}

__global__ __launch_bounds__(1024, 1) void attn_scan(
    const u16* __restrict__ y1bf,    // [B,T,M] prescaled by K2
    const u16* __restrict__ encbf,   // [B,T,M]
    const u16* __restrict__ whhbf,   // [1024,256]
    const u16* __restrict__ wdbf,    // [M,512]
    const float* __restrict__ Wd_b,  // [512]
    const float* __restrict__ vd,    // [512]
    const float* __restrict__ wtw,   // [513]
    const float* __restrict__ wtb,   // [1]
    const float* __restrict__ Wih,   // [1024]
    const float* __restrict__ bih,   // [1024]
    const float* __restrict__ bhh,   // [1024]
    const float* __restrict__ yin,   // [B,T]
    const float* __restrict__ gwenc, // [B,256]
    float* __restrict__ gx,          // [B][4][576]: 512 x1-partial + 64 dnew
    float* __restrict__ st,          // [B][4][4]: m_q, s_q, n_q, pad
    u32* __restrict__ flags,         // [B][32]: [0..3]=flagS, [8..11]=flagP
    float* __restrict__ out)         // [B,512]
{
  extern __shared__ char ldsraw[];
  u32* wdsl = (u32*)ldsraw;          // [512][64] swizzled bf16-pairs, 128 KiB

  __shared__ float x1_l[NM];
  __shared__ float d_l[NH];
  __shared__ float ds_f[128];        // [dn(64); sn(64)] of own h-slice
  __shared__ float l_sl[64];
  __shared__ float e_sl[64];
  __shared__ float whh_d_l[256];
  __shared__ float wih_l[256];
  __shared__ float bb_l[256];
  __shared__ float wdb_l[NM];
  __shared__ float wenc_sl[64];
  __shared__ float ct_red[NM];

  const int tid = threadIdx.x;
  const int bid = blockIdx.x;
  const int xcd = bid & 7, ii = bid >> 3;
  const int b = (xcd << 3) | (ii >> 2);   // 4 WGs of a batch on one XCD (locality only)
  const int q = ii & 3;
  const int w = tid >> 6, l = tid & 63;

  // ---- one-time init ----
  if (tid < 512) wdb_l[tid] = Wd_b[tid];
  if (tid < 256) {
    int g = tid >> 6, h = tid & 63;
    int r = g * 256 + q * 64 + h;
    wih_l[tid] = Wih[r];
    bb_l[tid] = bih[r] + bhh[r];
  }
  if (tid < 64) wenc_sl[tid] = gwenc[b * NT + q * 64 + tid];
  float vr[8];
  #pragma unroll
  for (int j = 0; j < 8; ++j) vr[j] = vd[l + 64 * j];
  float sv = 0.0f;
  #pragma unroll
  for (int j = 0; j < 8; ++j) sv += vr[j];
  #pragma unroll
  for (int off = 32; off > 0; off >>= 1) sv += __shfl_xor(sv, off, 64);
  const float Svd = sv;
  const float wtw512 = wtw[NM];
  const float wtb0 = wtb[0];

  // stage Wd column-slice into LDS as swizzled bf16 pairs:
  // k_local in [0,128): col = k<64 ? q*64+k : 256+q*64+(k-64)
  // pair p = k/2; granule g=p>>2; phys granule = g ^ (m&15)
  {
    int m = tid >> 1, kh = tid & 1;
    for (int j = 0; j < 32; ++j) {
      int p = kh * 32 + j;
      int k0 = 2 * p, k1 = 2 * p + 1;
      int c0 = (k0 < 64) ? q * 64 + k0 : 256 + q * 64 + (k0 - 64);
      int c1 = (k1 < 64) ? q * 64 + k1 : 256 + q * 64 + (k1 - 64);
      u32 lo = wdbf[m * 512 + c0];
      u32 hi = wdbf[m * 512 + c1];
      int g = p >> 2, pg = g ^ (m & 15);
      wdsl[m * 64 + pg * 4 + (p & 3)] = lo | (hi << 16);
    }
  }

  float s_reg = 0.0f;    // tid<64: own cell state c[h]
  float out_acc = 0.0f;  // tid<512: own m's running sum of c_t
  __syncthreads();

  float* gxb = gx + b * 2304;
  float* stb = st + b * 16;
  u32* fS = flags + b * 32;
  u32* fP = flags + b * 32 + 8;

  #pragma unroll 1
  for (int t = 0; t < NT; ++t) {
    // ---- wait for prev-step partials; read + assemble x1, d ----
    pollflags(fP, (u32)t);
    if (tid < 512) {
      const float* p = gxb + tid;
      float a0, a1, a2, a3;
      unc_ld1x4(p, p + 576, p + 1152, p + 1728, a0, a1, a2, a3);
      x1_l[tid] = K2 * (wdb_l[tid] + ((a0 + a1) + (a2 + a3)));
    } else if (tid < 768) {
      int h = tid - 512;
      d_l[h] = unc_ld1(gxb + (h >> 6) * 576 + 512 + (h & 63));
    }
    __syncthreads();  // (1)

    // ---- l_it over own 64-te slice (all 16 waves, 4 te each) ----
    float x1r[8];
    #pragma unroll
    for (int j = 0; j < 8; ++j) x1r[j] = x1_l[l + 64 * j];
    {
      const u16* yrow = y1bf + ((size_t)(b * NT + q * 64 + w * 4) << 9);
      #pragma unroll
      for (int i = 0; i < 4; ++i) {
        float a = 0.0f;
        #pragma unroll
        for (int j = 0; j < 8; ++j) {
          float yv = bf2f(yrow[i * 512 + l + 64 * j]);
          float e = __builtin_amdgcn_exp2f(x1r[j] + yv);
          a = fmaf(vr[j], __builtin_amdgcn_rcpf(1.0f + e), a);
        }
        #pragma unroll
        for (int off = 32; off > 0; off >>= 1) a += __shfl_xor(a, off, 64);
        if (l == i) l_sl[w * 4 + i] = Svd - 2.0f * a;
      }
    }
    __syncthreads();  // (2)

    // ---- wave0: slice softmax stats; store + flag (2-phase) ----
    if (w == 0) {
      float v = l_sl[l];
      float mq = v;
      #pragma unroll
      for (int off = 32; off > 0; off >>= 1) mq = fmaxf(mq, __shfl_xor(mq, off, 64));
      float e = __builtin_amdgcn_exp2f((v - mq) * LOG2E);
      e_sl[l] = e;
      float sq = e, nq = e * wenc_sl[l];
      #pragma unroll
      for (int off = 32; off > 0; off >>= 1) {
        sq += __shfl_xor(sq, off, 64);
        nq += __shfl_xor(nq, off, 64);
      }
      if (l == 0) {
        f32x4 quad = {mq, sq, nq, 0.0f};
        unc_st4(stb + q * 4, quad);
        drain_vmem();
        unc_st1u(fS + q, (u32)(t + 1));
      }
    } else {
      // ---- waves 1..15: Whh·d GEMV (hides the stats round-trip) ----
      #pragma unroll 1
      for (int pass = 0; pass < 2; ++pass) {
        int slot = (pass == 0) ? (tid - 64) : (tid - 64 + 960);
        if (pass == 1 && tid >= 128) break;
        int rl = slot >> 2, kq = slot & 3;
        const u16* wr = whhbf + (size_t)((rl >> 6) * 256 + q * 64 + (rl & 63)) * 256 + kq * 64;
        float a = 0.0f;
        #pragma unroll
        for (int c8 = 0; c8 < 8; ++c8) {
          short8v wv = *(const short8v*)(wr + c8 * 8);
          #pragma unroll
          for (int jj = 0; jj < 8; ++jj)
            a = fmaf(bf2f((u16)wv[jj]), d_l[kq * 64 + c8 * 8 + jj], a);
        }
        a += __shfl_xor(a, 1, 64);
        a += __shfl_xor(a, 2, 64);
        if (kq == 0) whh_d_l[rl] = a;
      }
    }

    // ---- all threads: poll stats, merge softmax, yt ----
    pollflags(fS, (u32)(t + 1));
    f32x4 s0 = unc_ld4f(stb + 0);
    f32x4 s1 = unc_ld4f(stb + 4);
    f32x4 s2 = unc_ld4f(stb + 8);
    f32x4 s3 = unc_ld4f(stb + 12);
    float mx = fmaxf(fmaxf(s0[0], s1[0]), fmaxf(s2[0], s3[0]));
    float w0 = __builtin_amdgcn_exp2f((s0[0] - mx) * LOG2E);
    float w1 = __builtin_amdgcn_exp2f((s1[0] - mx) * LOG2E);
    float w2 = __builtin_amdgcn_exp2f((s2[0] - mx) * LOG2E);
    float w3 = __builtin_amdgcn_exp2f((s3[0] - mx) * LOG2E);
    float den = fmaf(s0[1], w0, fmaf(s1[1], w1, fmaf(s2[1], w2, s3[1] * w3)));
    float rden = __builtin_amdgcn_rcpf(den);
    float nsum = fmaf(s0[2], w0, fmaf(s1[2], w1, fmaf(s2[2], w2, s3[2] * w3)));
    float yt = nsum * rden + wtw512 * yin[b * NT + t] + wtb0;
    float wq = (q == 0) ? w0 : (q == 1) ? w1 : (q == 2) ? w2 : w3;
    float sc_q = wq * rden;
    __syncthreads();  // (3) whh_d_l + e_sl ready

    // ---- cell update (wave0, 64 threads) ----
    if (tid < 64) {
      int h = tid;
      float gi = sigmoid_fast(whh_d_l[h]       + yt * wih_l[h]       + bb_l[h]);
      float gf = sigmoid_fast(whh_d_l[64 + h]  + yt * wih_l[64 + h]  + bb_l[64 + h]);
      float gg = tanh_fast   (whh_d_l[128 + h] + yt * wih_l[128 + h] + bb_l[128 + h]);
      float go = sigmoid_fast(whh_d_l[192 + h] + yt * wih_l[192 + h] + bb_l[192 + h]);
      float sn = gf * s_reg + gi * gg;
      s_reg = sn;
      float dn = go * tanh_fast(sn);
      ds_f[h] = dn;
      ds_f[64 + h] = sn;
      unc_st1(gxb + q * 576 + 512 + h, dn);
    }
    __syncthreads();  // (4)

    // ---- partial-x1 GEMV from LDS Wd-slice ----
    {
      int m = tid >> 1, kh = tid & 1;
      float a = 0.0f;
      #pragma unroll
      for (int i = 0; i < 8; ++i) {
        int g = kh * 8 + i, pg = g ^ (m & 15);
        u32x4 wv = *(const u32x4*)(wdsl + m * 64 + pg * 4);
        const f32x4 dv0 = *(const f32x4*)(ds_f + kh * 64 + i * 8);
        const f32x4 dv1 = *(const f32x4*)(ds_f + kh * 64 + i * 8 + 4);
        #pragma unroll
        for (int n = 0; n < 4; ++n) {
          u32 v = wv[n];
          float wlo = bits2f(v << 16);
          float whi = bits2f(v & 0xffff0000u);
          float dlo = (n < 2) ? dv0[2 * n] : dv1[2 * n - 4];
          float dhi = (n < 2) ? dv0[2 * n + 1] : dv1[2 * n - 3];
          a = fmaf(wlo, dlo, a);
          a = fmaf(whi, dhi, a);
        }
      }
      a += __shfl_xor(a, 1, 64);
      if (kh == 0) unc_st1(gxb + q * 576 + m, a);
    }
    drain_vmem();
    __syncthreads();  // (6) all waves drained
    if (tid == 0) unc_st1u(fP + q, (u32)(t + 1));

    // ---- c_t partial over own te-slice (off critical path) ----
    {
      int c = tid >> 9, m = tid & 511;
      const u16* ep = encbf + ((size_t)(b * NT + q * 64 + c * 32) << 9) + m;
      float a = 0.0f;
      #pragma unroll 8
      for (int i = 0; i < 32; ++i)
        a = fmaf(bf2f(ep[(size_t)i * 512]), e_sl[c * 32 + i], a);
      if (c) ct_red[m] = a;
      __syncthreads();  // (7)
      if (!c) out_acc += (a + ct_red[m]) * sc_q;
    }
  }

  if (tid < 512)
    __hip_atomic_fetch_add(&out[b * NM + tid], out_acc,
                           __ATOMIC_RELAXED, __HIP_MEMORY_SCOPE_SYSTEM);
}

extern "C" void kernel_launch(void* const* d_in, const int* in_sizes, int n_in,
                              void* d_out, int out_size, void* d_ws, size_t ws_size,
                              hipStream_t stream) {
  const float* enc  = (const float*)d_in[0];
  const float* yin  = (const float*)d_in[1];
  const float* Wd_w = (const float*)d_in[2];
  const float* Wd_b = (const float*)d_in[3];
  const float* Ud_w = (const float*)d_in[4];
  const float* vd_w = (const float*)d_in[5];
  const float* wt_w = (const float*)d_in[6];
  const float* wt_b = (const float*)d_in[7];
  const float* Wih  = (const float*)d_in[8];
  const float* Whh  = (const float*)d_in[9];
  const float* bih  = (const float*)d_in[10];
  const float* bhh  = (const float*)d_in[11];

  char* ws = (char*)d_ws;
  u16*   y1bf  = (u16*)(ws);                      // 16,777,216
  u16*   encbf = (u16*)(ws + 16777216);           // 16,777,216
  u16*   udbf  = (u16*)(ws + 33554432);           // 524,288
  u16*   wdbf  = (u16*)(ws + 34078720);           // 524,288
  u16*   whhbf = (u16*)(ws + 34603008);           // 524,288
  float* gwenc = (float*)(ws + 35127296);         // 65,536
  float* gx    = (float*)(ws + 35192832);         // 589,824
  float* st    = (float*)(ws + 35782656);         // 4,096
  u32*   flags = (u32*)(ws + 35786752);           // 8,192

  // zero mutable state: gx, st, flags; and d_out (atomic accumulation target)
  hipMemsetAsync(ws + 35192832, 0, 602112, stream);
  hipMemsetAsync(d_out, 0, (size_t)out_size * sizeof(float), stream);

  convert_f32_bf16<<<8388608 / 256, 256, 0, stream>>>(enc, encbf, 8388608);
  convert_f32_bf16<<<262144 / 256, 256, 0, stream>>>(Ud_w, udbf, 262144);
  convert_f32_bf16<<<262144 / 256, 256, 0, stream>>>(Wd_w, wdbf, 262144);
  convert_f32_bf16<<<262144 / 256, 256, 0, stream>>>(Whh, whhbf, 262144);
  gemm_y1<<<dim3(256, 8), 256, 0, stream>>>(encbf, udbf, y1bf);
  wenc_kernel<<<64, 256, 0, stream>>>(encbf, wt_w, gwenc);

  hipFuncSetAttribute((const void*)attn_scan,
                      hipFuncAttributeMaxDynamicSharedMemorySize, 131072);
  attn_scan<<<256, 1024, 131072, stream>>>(y1bf, encbf, whhbf, wdbf, Wd_b, vd_w,
                                           wt_w, wt_b, Wih, bih, bhh, yin, gwenc,
                                           gx, st, flags, (float*)d_out);
}